// Round 4
// baseline (57.585 us; speedup 1.0000x reference)
//
#include <hip/hip_runtime.h>

// Fused 6-layer MLP, v4: v2 structure + bf16-packed W1 in LDS (halves LDS
// instructions and bytes) + depth-2 x prefetch.
// Block = 256 threads = 64 rows x 4 k-sublanes, grid = 1024.
//   Per iter: 1 global float4 (x, 64B/line/row fully consumed), 6 ds_read_b128
//   (48 bf16 W1 vals, 16-way broadcast, conflict-free), 48 FMAs, 24 unpack shl.
//   hi bf16 used as asfloat(u) directly (junk low bits <= bf16 ulp).

__device__ __forceinline__ float ftanh(float v) {
    float e = __expf(2.0f * v);
    return 1.0f - 2.0f / (e + 1.0f);
}

__device__ __forceinline__ uint32_t bfpack(float lo, float hi) {
    uint32_t ul = __float_as_uint(lo);
    uint32_t uh = __float_as_uint(hi);
    ul += 0x7fffu + ((ul >> 16) & 1u);   // RTN to bf16
    uh += 0x7fffu + ((uh >> 16) & 1u);
    return (ul >> 16) | (uh & 0xffff0000u);
}

__global__ __launch_bounds__(256, 4)
void mlp_fused4(const float* __restrict__ x,
                const float* __restrict__ W1, const float* __restrict__ b1,
                const float* __restrict__ W2, const float* __restrict__ b2,
                const float* __restrict__ W3, const float* __restrict__ b3,
                const float* __restrict__ W4, const float* __restrict__ b4,
                const float* __restrict__ W5, const float* __restrict__ b5,
                const float* __restrict__ W6, const float* __restrict__ b6,
                float* __restrict__ out)
{
    __shared__ uint32_t ldsW[4704];        // 784 rows x 6 u32 (12 bf16) = 18816 B

    const int tid = threadIdx.x;

    // ---- stage W1 into LDS as packed bf16 pairs ----
    const float2* w1v = (const float2*)W1;
    for (int t = tid; t < 4704; t += 256) {
        float2 p = w1v[t];
        ldsW[t] = bfpack(p.x, p.y);
    }
    __syncthreads();

    const int lane = tid & 63;
    const int wave = tid >> 6;
    const int r    = lane >> 2;            // row within 16-row wave group
    const int sub  = lane & 3;             // k-quarter within 64B line
    const int row  = (blockIdx.x << 6) + (wave << 4) + r;

    float acc[12];
#pragma unroll
    for (int j = 0; j < 12; ++j) acc[j] = 0.f;

    const float4* xrow = (const float4*)(x + (size_t)row * 784);
    const uint4*  wq   = (const uint4*)ldsW;

    // depth-2 software pipeline on x
    float4 f0 = xrow[sub];
    float4 f1 = xrow[4 + sub];

    for (int i = 0; i < 49; ++i) {
        float4 f2 = (i < 47) ? xrow[(i + 2) * 4 + sub] : f0;

        // 24 u32 = W1 rows [i*16+sub*4 .. +4), 6 u32 (12 bf16) each
        uint4 q[6];
#pragma unroll
        for (int c = 0; c < 6; ++c) q[c] = wq[i * 24 + sub * 6 + c];

#pragma unroll
        for (int dk = 0; dk < 4; ++dk) {
            float xx = (dk == 0) ? f0.x : (dk == 1) ? f0.y : (dk == 2) ? f0.z : f0.w;
#pragma unroll
            for (int c = 0; c < 6; ++c) {
                int m = 6 * dk + c;                       // u32 index 0..23
                uint32_t u = (m & 3) == 0 ? q[m >> 2].x :
                             (m & 3) == 1 ? q[m >> 2].y :
                             (m & 3) == 2 ? q[m >> 2].z : q[m >> 2].w;
                acc[2 * c]     += xx * __uint_as_float(u << 16);
                acc[2 * c + 1] += xx * __uint_as_float(u);   // junk low bits ~ bf16 ulp
            }
        }
        f0 = f1;
        f1 = f2;
    }

    // ---- reduce 4 sub-partials + bias + tanh ----
    float h1[12];
#pragma unroll
    for (int j = 0; j < 12; ++j) {
        float z = acc[j];
        z += __shfl_xor(z, 1);
        z += __shfl_xor(z, 2);
        h1[j] = ftanh(z + b1[j]);
    }

    // ---- tiny layers 2..6 (redundant on sub-lanes; uniform weights -> s_load) ----
    float h2[10];
#pragma unroll
    for (int m = 0; m < 10; ++m) {
        float s = b2[m];
#pragma unroll
        for (int j = 0; j < 12; ++j) s += h1[j] * W2[j * 10 + m];
        h2[m] = ftanh(s);
    }
    float h3[8];
#pragma unroll
    for (int m = 0; m < 8; ++m) {
        float s = b3[m];
#pragma unroll
        for (int j = 0; j < 10; ++j) s += h2[j] * W3[j * 8 + m];
        h3[m] = ftanh(s);
    }
    float h4[6];
#pragma unroll
    for (int m = 0; m < 6; ++m) {
        float s = b4[m];
#pragma unroll
        for (int j = 0; j < 8; ++j) s += h3[j] * W4[j * 6 + m];
        h4[m] = ftanh(s);
    }
    float h5[4];
#pragma unroll
    for (int m = 0; m < 4; ++m) {
        float s = b5[m];
#pragma unroll
        for (int j = 0; j < 6; ++j) s += h4[j] * W5[j * 4 + m];
        h5[m] = ftanh(s);
    }
    float o[10];
#pragma unroll
    for (int m = 0; m < 10; ++m) {
        float s = b6[m];
#pragma unroll
        for (int j = 0; j < 4; ++j) s += h5[j] * W6[j * 10 + m];
        o[m] = s;   // logits
    }

    // ---- vectorized stores, round-robined over sub ----
    const size_t H1 = 655360, H2 = 1441792, H3 = 2097152, H4 = 2621440, H5 = 3014656;
    float2* po  = (float2*)(out +      (size_t)row * 10);
    float4* ph1 = (float4*)(out + H1 + (size_t)row * 12);
    float2* ph2 = (float2*)(out + H2 + (size_t)row * 10);
    float4* ph3 = (float4*)(out + H3 + (size_t)row * 8);
    float2* ph4 = (float2*)(out + H4 + (size_t)row * 6);
    float4* ph5 = (float4*)(out + H5 + (size_t)row * 4);

    if (sub == 0) {
        po[0]  = make_float2(o[0], o[1]);
        po[4]  = make_float2(o[8], o[9]);
        ph2[0] = make_float2(h2[0], h2[1]);
        ph2[4] = make_float2(h2[8], h2[9]);
        ph4[1] = make_float2(h4[2], h4[3]);
    } else if (sub == 1) {
        po[1]  = make_float2(o[2], o[3]);
        ph1[0] = make_float4(h1[0], h1[1], h1[2], h1[3]);
        ph2[1] = make_float2(h2[2], h2[3]);
        ph3[0] = make_float4(h3[0], h3[1], h3[2], h3[3]);
        ph4[2] = make_float2(h4[4], h4[5]);
    } else if (sub == 2) {
        po[2]  = make_float2(o[4], o[5]);
        ph1[1] = make_float4(h1[4], h1[5], h1[6], h1[7]);
        ph2[2] = make_float2(h2[4], h2[5]);
        ph3[1] = make_float4(h3[4], h3[5], h3[6], h3[7]);
        ph5[0] = make_float4(h5[0], h5[1], h5[2], h5[3]);
    } else {
        po[3]  = make_float2(o[6], o[7]);
        ph1[2] = make_float4(h1[8], h1[9], h1[10], h1[11]);
        ph2[3] = make_float2(h2[6], h2[7]);
        ph4[0] = make_float2(h4[0], h4[1]);
    }
}

extern "C" void kernel_launch(void* const* d_in, const int* in_sizes, int n_in,
                              void* d_out, int out_size, void* d_ws, size_t ws_size,
                              hipStream_t stream) {
    (void)in_sizes; (void)n_in; (void)d_ws; (void)ws_size; (void)out_size;
    mlp_fused4<<<1024, 256, 0, stream>>>(
        (const float*)d_in[0],
        (const float*)d_in[1],  (const float*)d_in[2],
        (const float*)d_in[3],  (const float*)d_in[4],
        (const float*)d_in[5],  (const float*)d_in[6],
        (const float*)d_in[7],  (const float*)d_in[8],
        (const float*)d_in[9],  (const float*)d_in[10],
        (const float*)d_in[11], (const float*)d_in[12],
        (float*)d_out);
}

// Round 5
// 53.234 us; speedup vs baseline: 1.0817x; 1.0817x over previous
//
#include <hip/hip_runtime.h>

// Fused 6-layer MLP, v5: v0 structure (SGPR W1, k-split across 4 waves) with
// the x-load fixed to consume full 64B lines via 4 back-to-back float4 loads
// into registers (MSHR-merged; no cache-timing dependence -> FETCH = 1.0x).
// Block = 256 threads = 4 waves, 64 rows/block; wave w covers k in
// [w*196, w*196+196) = 12 groups of 16k + 4k tail. Lane = row.
// W1/W2../biases all wave-uniform -> s_load, SGPR operands: zero VALU/LDS cost.
// Partials reduced via 13-padded LDS + shfl; vectorized epilogue from v2.

__device__ __forceinline__ float ftanh(float v) {
    float e = __expf(2.0f * v);
    return 1.0f - 2.0f / (e + 1.0f);
}

__global__ __launch_bounds__(256, 4)
void mlp_fused5(const float* __restrict__ x,
                const float* __restrict__ W1, const float* __restrict__ b1,
                const float* __restrict__ W2, const float* __restrict__ b2,
                const float* __restrict__ W3, const float* __restrict__ b3,
                const float* __restrict__ W4, const float* __restrict__ b4,
                const float* __restrict__ W5, const float* __restrict__ b5,
                const float* __restrict__ W6, const float* __restrict__ b6,
                float* __restrict__ out)
{
    __shared__ float lds[64][4][13];   // [row][wave][j(pad 12->13)]

    const int tid  = threadIdx.x;
    const int wave = __builtin_amdgcn_readfirstlane(tid >> 6);  // uniform -> s_load W1
    const int lane = tid & 63;
    const int row0 = blockIdx.x << 6;

    // ---------- layer 1 partials: wave-local k-range, lane = row ----------
    float acc[12];
#pragma unroll
    for (int j = 0; j < 12; ++j) acc[j] = 0.f;

    const float4* xv4 = (const float4*)(x + (size_t)(row0 + lane) * 784 + wave * 196);
    const float*  w1p = W1 + wave * 196 * 12;   // wave-uniform base

    // software pipeline: current 64B group in c0..c3, next in n0..n3
    float4 c0 = xv4[0], c1 = xv4[1], c2 = xv4[2], c3 = xv4[3];

#define FMA16(wkbase)                                                          \
    do {                                                                       \
        const float* wk = (wkbase);                                            \
        _Pragma("unroll")                                                      \
        for (int dk = 0; dk < 16; ++dk) {                                      \
            float xx = (dk >> 2) == 0 ? ((dk & 3) == 0 ? c0.x : (dk & 3) == 1 ? c0.y : (dk & 3) == 2 ? c0.z : c0.w) \
                     : (dk >> 2) == 1 ? ((dk & 3) == 0 ? c1.x : (dk & 3) == 1 ? c1.y : (dk & 3) == 2 ? c1.z : c1.w) \
                     : (dk >> 2) == 2 ? ((dk & 3) == 0 ? c2.x : (dk & 3) == 1 ? c2.y : (dk & 3) == 2 ? c2.z : c2.w) \
                     :                  ((dk & 3) == 0 ? c3.x : (dk & 3) == 1 ? c3.y : (dk & 3) == 2 ? c3.z : c3.w); \
            _Pragma("unroll")                                                  \
            for (int j = 0; j < 12; ++j) acc[j] += xx * wk[dk * 12 + j];       \
        }                                                                      \
    } while (0)

    for (int t = 0; t < 11; ++t) {
        float4 n0 = xv4[t * 4 + 4];
        float4 n1 = xv4[t * 4 + 5];
        float4 n2 = xv4[t * 4 + 6];
        float4 n3 = xv4[t * 4 + 7];
        FMA16(w1p + t * 192);
        c0 = n0; c1 = n1; c2 = n2; c3 = n3;
    }
    float4 tl = xv4[48];               // k-tail: 4 values
    FMA16(w1p + 11 * 192);
    {
        const float* wk = w1p + 2304;  // k = 192..195 within wave chunk
#pragma unroll
        for (int dk = 0; dk < 4; ++dk) {
            float xx = dk == 0 ? tl.x : dk == 1 ? tl.y : dk == 2 ? tl.z : tl.w;
#pragma unroll
            for (int j = 0; j < 12; ++j) acc[j] += xx * wk[dk * 12 + j];
        }
    }
#undef FMA16

#pragma unroll
    for (int j = 0; j < 12; ++j) lds[lane][wave][j] = acc[j];
    __syncthreads();

    // ---------- epilogue: 4 threads per row ----------
    const int r   = tid >> 2;      // local row 0..63
    const int sub = tid & 3;       // partial index / store split
    const int row = row0 + r;

    float h1[12];
#pragma unroll
    for (int j = 0; j < 12; ++j) {
        float z = lds[r][sub][j];
        z += __shfl_xor(z, 1);
        z += __shfl_xor(z, 2);     // all 4 lanes hold full sum
        h1[j] = ftanh(z + b1[j]);
    }

    float h2[10];
#pragma unroll
    for (int m = 0; m < 10; ++m) {
        float s = b2[m];
#pragma unroll
        for (int j = 0; j < 12; ++j) s += h1[j] * W2[j * 10 + m];
        h2[m] = ftanh(s);
    }
    float h3[8];
#pragma unroll
    for (int m = 0; m < 8; ++m) {
        float s = b3[m];
#pragma unroll
        for (int j = 0; j < 10; ++j) s += h2[j] * W3[j * 8 + m];
        h3[m] = ftanh(s);
    }
    float h4[6];
#pragma unroll
    for (int m = 0; m < 6; ++m) {
        float s = b4[m];
#pragma unroll
        for (int j = 0; j < 8; ++j) s += h3[j] * W4[j * 6 + m];
        h4[m] = ftanh(s);
    }
    float h5[4];
#pragma unroll
    for (int m = 0; m < 4; ++m) {
        float s = b5[m];
#pragma unroll
        for (int j = 0; j < 6; ++j) s += h4[j] * W5[j * 4 + m];
        h5[m] = ftanh(s);
    }
    float o[10];
#pragma unroll
    for (int m = 0; m < 10; ++m) {
        float s = b6[m];
#pragma unroll
        for (int j = 0; j < 4; ++j) s += h5[j] * W6[j * 10 + m];
        o[m] = s;   // logits
    }

    // ---------- vectorized stores, round-robined over sub ----------
    const size_t H1 = 655360, H2 = 1441792, H3 = 2097152, H4 = 2621440, H5 = 3014656;
    float2* po  = (float2*)(out +      (size_t)row * 10);
    float4* ph1 = (float4*)(out + H1 + (size_t)row * 12);
    float2* ph2 = (float2*)(out + H2 + (size_t)row * 10);
    float4* ph3 = (float4*)(out + H3 + (size_t)row * 8);
    float2* ph4 = (float2*)(out + H4 + (size_t)row * 6);
    float4* ph5 = (float4*)(out + H5 + (size_t)row * 4);

    if (sub == 0) {
        po[0]  = make_float2(o[0], o[1]);
        po[4]  = make_float2(o[8], o[9]);
        ph2[0] = make_float2(h2[0], h2[1]);
        ph2[4] = make_float2(h2[8], h2[9]);
        ph4[1] = make_float2(h4[2], h4[3]);
    } else if (sub == 1) {
        po[1]  = make_float2(o[2], o[3]);
        ph1[0] = make_float4(h1[0], h1[1], h1[2], h1[3]);
        ph2[1] = make_float2(h2[2], h2[3]);
        ph3[0] = make_float4(h3[0], h3[1], h3[2], h3[3]);
        ph4[2] = make_float2(h4[4], h4[5]);
    } else if (sub == 2) {
        po[2]  = make_float2(o[4], o[5]);
        ph1[1] = make_float4(h1[4], h1[5], h1[6], h1[7]);
        ph2[2] = make_float2(h2[4], h2[5]);
        ph3[1] = make_float4(h3[4], h3[5], h3[6], h3[7]);
        ph5[0] = make_float4(h5[0], h5[1], h5[2], h5[3]);
    } else {
        po[3]  = make_float2(o[6], o[7]);
        ph1[2] = make_float4(h1[8], h1[9], h1[10], h1[11]);
        ph2[3] = make_float2(h2[6], h2[7]);
        ph4[0] = make_float2(h4[0], h4[1]);
    }
}

extern "C" void kernel_launch(void* const* d_in, const int* in_sizes, int n_in,
                              void* d_out, int out_size, void* d_ws, size_t ws_size,
                              hipStream_t stream) {
    (void)in_sizes; (void)n_in; (void)d_ws; (void)ws_size; (void)out_size;
    mlp_fused5<<<1024, 256, 0, stream>>>(
        (const float*)d_in[0],
        (const float*)d_in[1],  (const float*)d_in[2],
        (const float*)d_in[3],  (const float*)d_in[4],
        (const float*)d_in[5],  (const float*)d_in[6],
        (const float*)d_in[7],  (const float*)d_in[8],
        (const float*)d_in[9],  (const float*)d_in[10],
        (const float*)d_in[11], (const float*)d_in[12],
        (float*)d_out);
}

// Round 6
// 45.860 us; speedup vs baseline: 1.2557x; 1.1608x over previous
//
#include <hip/hip_runtime.h>

// Fused 6-layer MLP, v7: v2's exact main-loop structure (coalesced 64B-line x
// reads, LDS-broadcast W1) with latency-hiding fixes only:
//   - 512-thread blocks (8 waves) -> 6-8 waves/SIMD (was 4), LDS 37.6KB still
//     allows up to 4 blocks/CU.
//   - explicit depth-2 branchless x prefetch (clamped index).
// Block = 512 threads = 128 rows x 4 k-sublanes. Grid = 512 blocks.

__device__ __forceinline__ float ftanh(float v) {
    float e = __expf(2.0f * v);          // v_exp based; overflow -> inf -> 1.0
    return 1.0f - 2.0f / (e + 1.0f);
}

__global__ __launch_bounds__(512, 6)
void mlp_fused7(const float* __restrict__ x,
                const float* __restrict__ W1, const float* __restrict__ b1,
                const float* __restrict__ W2, const float* __restrict__ b2,
                const float* __restrict__ W3, const float* __restrict__ b3,
                const float* __restrict__ W4, const float* __restrict__ b4,
                const float* __restrict__ W5, const float* __restrict__ b5,
                const float* __restrict__ W6, const float* __restrict__ b6,
                float* __restrict__ out)
{
    __shared__ float4 ldsW1[2352];          // 784*12 floats = 37632 B

    const int tid = threadIdx.x;

    // ---- stage W1 into LDS (coalesced flat copy) ----
    const float4* w1v = (const float4*)W1;
    for (int t = tid; t < 2352; t += 512) ldsW1[t] = w1v[t];
    __syncthreads();

    const int lane = tid & 63;
    const int wave = tid >> 6;              // 0..7
    const int r    = lane >> 2;             // row within 16-row wave group
    const int sub  = lane & 3;              // k-quarter within 64B line
    const int row  = (blockIdx.x << 7) + (wave << 4) + r;

    // ---- layer 1: acc over k, 4 lanes per row, depth-2 prefetch ----
    float acc[12];
#pragma unroll
    for (int j = 0; j < 12; ++j) acc[j] = 0.f;

    const float4* xrow = (const float4*)(x + (size_t)row * 784);

    float4 f0 = xrow[sub];
    float4 f1 = xrow[4 + sub];

#pragma unroll 7
    for (int i = 0; i < 49; ++i) {
        int pf = (i + 2 < 49) ? (i + 2) : 47;        // branchless clamp
        float4 f2 = xrow[pf * 4 + sub];

        const float4* wb = ldsW1 + i * 48 + sub * 12;   // 4 W1 rows = 12 float4
#pragma unroll
        for (int dk = 0; dk < 4; ++dk) {
            float xx = (dk == 0) ? f0.x : (dk == 1) ? f0.y : (dk == 2) ? f0.z : f0.w;
            float4 w0 = wb[dk * 3 + 0];
            float4 w1 = wb[dk * 3 + 1];
            float4 w2 = wb[dk * 3 + 2];
            acc[0] += xx * w0.x;  acc[1] += xx * w0.y;  acc[2]  += xx * w0.z;  acc[3]  += xx * w0.w;
            acc[4] += xx * w1.x;  acc[5] += xx * w1.y;  acc[6]  += xx * w1.z;  acc[7]  += xx * w1.w;
            acc[8] += xx * w2.x;  acc[9] += xx * w2.y;  acc[10] += xx * w2.z;  acc[11] += xx * w2.w;
        }
        f0 = f1;
        f1 = f2;
    }

    // ---- reduce 4 sub-partials (within 4-lane group) + bias + tanh ----
    float h1[12];
#pragma unroll
    for (int j = 0; j < 12; ++j) {
        float z = acc[j];
        z += __shfl_xor(z, 1);
        z += __shfl_xor(z, 2);
        h1[j] = ftanh(z + b1[j]);
    }

    // ---- tiny layers 2..6 (redundant on all 4 sub-lanes; uniform W via s_load) ----
    float h2[10];
#pragma unroll
    for (int m = 0; m < 10; ++m) {
        float s = b2[m];
#pragma unroll
        for (int j = 0; j < 12; ++j) s += h1[j] * W2[j * 10 + m];
        h2[m] = ftanh(s);
    }

    float h3[8];
#pragma unroll
    for (int m = 0; m < 8; ++m) {
        float s = b3[m];
#pragma unroll
        for (int j = 0; j < 10; ++j) s += h2[j] * W3[j * 8 + m];
        h3[m] = ftanh(s);
    }

    float h4[6];
#pragma unroll
    for (int m = 0; m < 6; ++m) {
        float s = b4[m];
#pragma unroll
        for (int j = 0; j < 8; ++j) s += h3[j] * W4[j * 6 + m];
        h4[m] = ftanh(s);
    }

    float h5[4];
#pragma unroll
    for (int m = 0; m < 4; ++m) {
        float s = b5[m];
#pragma unroll
        for (int j = 0; j < 6; ++j) s += h4[j] * W5[j * 4 + m];
        h5[m] = ftanh(s);
    }

    float o[10];
#pragma unroll
    for (int m = 0; m < 10; ++m) {
        float s = b6[m];
#pragma unroll
        for (int j = 0; j < 4; ++j) s += h5[j] * W6[j * 10 + m];
        o[m] = s;   // logits
    }

    // ---- vectorized stores, round-robined over sub (compile-time reg indices) ----
    const size_t H1 = 655360, H2 = 1441792, H3 = 2097152, H4 = 2621440, H5 = 3014656;
    float2* po  = (float2*)(out +      (size_t)row * 10);   // 8B aligned (row*40B)
    float4* ph1 = (float4*)(out + H1 + (size_t)row * 12);   // 16B aligned (row*48B)
    float2* ph2 = (float2*)(out + H2 + (size_t)row * 10);
    float4* ph3 = (float4*)(out + H3 + (size_t)row * 8);
    float2* ph4 = (float2*)(out + H4 + (size_t)row * 6);
    float4* ph5 = (float4*)(out + H5 + (size_t)row * 4);

    if (sub == 0) {
        po[0]  = make_float2(o[0], o[1]);
        po[4]  = make_float2(o[8], o[9]);
        ph2[0] = make_float2(h2[0], h2[1]);
        ph2[4] = make_float2(h2[8], h2[9]);
        ph4[1] = make_float2(h4[2], h4[3]);
    } else if (sub == 1) {
        po[1]  = make_float2(o[2], o[3]);
        ph1[0] = make_float4(h1[0], h1[1], h1[2], h1[3]);
        ph2[1] = make_float2(h2[2], h2[3]);
        ph3[0] = make_float4(h3[0], h3[1], h3[2], h3[3]);
        ph4[2] = make_float2(h4[4], h4[5]);
    } else if (sub == 2) {
        po[2]  = make_float2(o[4], o[5]);
        ph1[1] = make_float4(h1[4], h1[5], h1[6], h1[7]);
        ph2[2] = make_float2(h2[4], h2[5]);
        ph3[1] = make_float4(h3[4], h3[5], h3[6], h3[7]);
        ph5[0] = make_float4(h5[0], h5[1], h5[2], h5[3]);
    } else {
        po[3]  = make_float2(o[6], o[7]);
        ph1[2] = make_float4(h1[8], h1[9], h1[10], h1[11]);
        ph2[3] = make_float2(h2[6], h2[7]);
        ph4[0] = make_float2(h4[0], h4[1]);
    }
}

extern "C" void kernel_launch(void* const* d_in, const int* in_sizes, int n_in,
                              void* d_out, int out_size, void* d_ws, size_t ws_size,
                              hipStream_t stream) {
    (void)in_sizes; (void)n_in; (void)d_ws; (void)ws_size; (void)out_size;
    mlp_fused7<<<512, 512, 0, stream>>>(
        (const float*)d_in[0],
        (const float*)d_in[1],  (const float*)d_in[2],
        (const float*)d_in[3],  (const float*)d_in[4],
        (const float*)d_in[5],  (const float*)d_in[6],
        (const float*)d_in[7],  (const float*)d_in[8],
        (const float*)d_in[9],  (const float*)d_in[10],
        (const float*)d_in[11], (const float*)d_in[12],
        (float*)d_out);
}